// Round 11
// baseline (267.449 us; speedup 1.0000x reference)
//
#include <hip/hip_runtime.h>
#include <hip/hip_fp16.h>

// GNN mean-aggregate + dual GEMM. N=50000, E=1.6M, DIM=128, fp32 in/out.
// Pipeline (4 launches): k_prep (cursors + pack W + x->f16 xt)
// -> k_bin (bucket bin) -> k_csort (per-bucket sort -> u16 CSR)
// -> k_gg (FUSED gather + MFMA GEMM; agg rows via LDS, d_out write-only).
// LEDGER:
//  - gather: random-access request-rate bound ~84us (R6 body frozen).
//    L2-resident tiled variants all SLOWER (R5 ~110, R8 103).
//  - single-pass atomic scatter CSR: 300us (R9, full-line RMW writes).
//  - dur_us includes ~42us harness ws-poison fill (fixed).
//  - R10 budget: gather 84 + bin/csort ~55 + prep 10 + gemm 15 + fill 42
//    + gaps 20 = 234.
// R11: fuse gather+gemm. Block=64 nodes=one gemm tile. Gather phase
// (4 waves x 16 serial nodes, R6 body) -> agg rows to LDS (stride-68
// pad: 256B-stride rows would 16-way conflict). Gemm phase: agg frags
// from LDS, x frags from xt. xt moved fully to ws so d_out is
// WRITE-ONLY (in-place abf would race: out-write clobbers x-halves
// other blocks still gather). Saves 12.5MB agg write + gemm A-read +
// one launch gap; gemm compute overlaps gather across blocks.

constexpr int DIM    = 128;
constexpr int NBMAX  = 512;    // coarse buckets (node>>7); N=50000 -> 391
constexpr int EPB    = 4096;   // edges per binning block (512 thr x 8)
constexpr int CAP    = 9216;   // entries per bucket (E[cnt]=8184, ~11 sigma)

typedef _Float16 half8 __attribute__((ext_vector_type(8)));
typedef __attribute__((ext_vector_type(4))) float f32x4;

__device__ __forceinline__ unsigned hadd2u(unsigned a, unsigned b) {
    __half2 ha = *reinterpret_cast<__half2*>(&a);
    __half2 hb = *reinterpret_cast<__half2*>(&b);
    __half2 r  = __hadd2(ha, hb);
    return *reinterpret_cast<unsigned*>(&r);
}
__device__ __forceinline__ unsigned hmul2u(unsigned a, __half2 s) {
    __half2 ha = *reinterpret_cast<__half2*>(&a);
    __half2 r  = __hmul2(ha, s);
    return *reinterpret_cast<unsigned*>(&r);
}
__device__ __forceinline__ unsigned packf16(float x, float y) {
    __half2 h = __floats2half2_rn(x, y);
    return *reinterpret_cast<unsigned*>(&h);
}

// --- K0: fused prep. (a) bucket cursors; (b) pack [Wn;Ws] -> Bp f16
// B-fragments; (c) x fp32 -> f16 xt rows (gather source + gemm x-frags). ---
__global__ __launch_bounds__(256) void k_prep(
    const float* __restrict__ Wn, const float* __restrict__ Ws,
    const float* __restrict__ x,
    unsigned short* __restrict__ Bp, int* __restrict__ bucket_cur,
    unsigned* __restrict__ xt, int nb, int n_nodes)
{
    int i = blockIdx.x * 256 + threadIdx.x;
    if (i < nb) bucket_cur[i] = i * CAP;
    if (i < 8 * 128 * 4 * 8) {
        int j    = i & 7;
        int quad = (i >> 3) & 3;
        int n    = (i >> 5) & 127;
        int kb   = i >> 12;
        int k = kb * 32 + quad * 8 + j;
        float v = (k < 128) ? Wn[k * 128 + n] : Ws[(k - 128) * 128 + n];
        __half h = __float2half_rn(v);
        Bp[i] = *reinterpret_cast<unsigned short*>(&h);
    }
    if (i < n_nodes * 64) {
        int n = i >> 6;
        int u = i & 63;
        float2 f = ((const float2*)(x + (size_t)n * DIM))[u];
        xt[(size_t)n * 64 + u] = packf16(f.x, f.y);
    }
}

// --- K1: bin endpoints into fixed-cap buckets. 512 threads, 4096
// edges/block. Entry = (full_node_id<<16) | nbr_id (bucket = e>>23,
// no gaddr staging). Per-wave LDS histogram -> global frontier alloc
// -> block-local LDS counting sort -> coalesced writeback. ---
__global__ __launch_bounds__(512) void k_bin(
    const int* __restrict__ edge, int* __restrict__ bucket_cur,
    unsigned* __restrict__ entries, int n_edges, int nb)
{
    __shared__ int lh[8][NBMAX];
    __shared__ int Lb[NBMAX];
    __shared__ int gb[NBMAX];
    __shared__ int sc[NBMAX];
    __shared__ unsigned sorted[2 * EPB];

    int t = threadIdx.x;
    int w = t >> 6;
    for (int i = t; i < 8 * NBMAX; i += 512) ((int*)lh)[i] = 0;
    __syncthreads();

    int e0 = blockIdx.x * EPB;
    int2 ev[8];
    #pragma unroll
    for (int k = 0; k < 8; k++) {
        int idx = e0 + k * 512 + t;
        if (idx < n_edges) {
            ev[k] = ((const int2*)edge)[idx];
            atomicAdd(&lh[w][ev[k].x >> 7], 1);
            atomicAdd(&lh[w][ev[k].y >> 7], 1);
        } else {
            ev[k].x = -1;
        }
    }
    __syncthreads();

    {
        int s = 0;
        #pragma unroll
        for (int ww = 0; ww < 8; ww++) s += lh[ww][t];
        sc[t] = s;
    }
    __syncthreads();
    for (int d = 1; d < 512; d <<= 1) {
        int v = (t >= d) ? sc[t - d] : 0;
        __syncthreads();
        if (t >= d) sc[t] += v;
        __syncthreads();
    }
    if (t < nb) {
        int tot = 0;
        #pragma unroll
        for (int ww = 0; ww < 8; ww++) tot += lh[ww][t];
        int L = sc[t] - tot;
        Lb[t] = L;
        gb[t] = tot ? atomicAdd(&bucket_cur[t], tot) : 0;
        int run = L;
        #pragma unroll
        for (int ww = 0; ww < 8; ww++) { int c = lh[ww][t]; lh[ww][t] = run; run += c; }
    }
    __syncthreads();

    #pragma unroll
    for (int k = 0; k < 8; k++) {
        int a = ev[k].x;
        if (a < 0) continue;
        int b = ev[k].y;
        int sa = atomicAdd(&lh[w][a >> 7], 1);
        sorted[sa] = ((unsigned)a << 16) | (unsigned)b;
        int sb = atomicAdd(&lh[w][b >> 7], 1);
        sorted[sb] = ((unsigned)b << 16) | (unsigned)a;
    }
    __syncthreads();

    int cntb = sc[511];
    for (int p = t; p < cntb; p += 512) {
        unsigned e = sorted[p];
        int bk = (int)(e >> 23);
        entries[gb[bk] + p - Lb[bk]] = e;
    }
}

// --- K2: per-bucket counting sort, 512 threads, 8-way privatized cursors ---
__global__ __launch_bounds__(512) void k_csort(
    const unsigned* __restrict__ entries, const int* __restrict__ bucket_cur,
    unsigned* __restrict__ offsets, int* __restrict__ degs,
    unsigned short* __restrict__ nbr, int n_nodes)
{
    int b    = blockIdx.x;
    int base = b * CAP;
    int cnt  = bucket_cur[b] - base;
    __shared__ int lh[8][128];
    __shared__ int scn[128];
    int t = threadIdx.x;
    int w = t >> 6;
    for (int i = t; i < 8 * 128; i += 512) ((int*)lh)[i] = 0;
    __syncthreads();
    for (int i = t; i < cnt; i += 512)
        atomicAdd(&lh[w][(entries[base + i] >> 16) & 127], 1);
    __syncthreads();
    int tot = 0;
    if (t < 128) {
        #pragma unroll
        for (int ww = 0; ww < 8; ww++) tot += lh[ww][t];
        scn[t] = tot;
    }
    __syncthreads();
    for (int d = 1; d < 128; d <<= 1) {
        int u = (t >= d && t < 128) ? scn[t - d] : 0;
        __syncthreads();
        if (t >= d && t < 128) scn[t] += u;
        __syncthreads();
    }
    if (t < 128) {
        int excl = scn[t] - tot;
        int node = (b << 7) + t;
        if (node < n_nodes) {
            offsets[node] = (unsigned)(base + excl);
            degs[node]    = tot;
        }
        int run = excl;
        #pragma unroll
        for (int ww = 0; ww < 8; ww++) { int c = lh[ww][t]; lh[ww][t] = run; run += c; }
    }
    __syncthreads();
    for (int i = t; i < cnt; i += 512) {
        unsigned e = entries[base + i];
        int slot = atomicAdd(&lh[w][(e >> 16) & 127], 1);
        nbr[base + slot] = (unsigned short)(e & 0xFFFFu);
    }
}

// --- K3 (R11): FUSED gather + MFMA GEMM. Block = 64 nodes.
// Phase 1: each of 4 waves runs the frozen R6 gather body for 16 nodes
// serially (1 wave/node), writing the scaled mean row (256B f16) to LDS
// at uint-stride 68 (bank-conflict pad). Phase 2: per-wave 16-row MFMA;
// agg frags (kb 0..3) from LDS, x frags (kb 4..7) from xt; bias; write
// fp32 out (d_out write-only). ---
__global__ __launch_bounds__(256) void k_gg(
    const unsigned* __restrict__ offsets,
    const int* __restrict__ degs,
    const unsigned short* __restrict__ nbr,
    const unsigned* __restrict__ xt,
    const unsigned short* __restrict__ Bp,
    const float* __restrict__ bias,
    float* __restrict__ out, int n_nodes)
{
    __shared__ unsigned aS[64 * 68];   // 64 agg rows, stride 68 uints (pad)
    int wave = threadIdx.x >> 6;
    int lane = threadIdx.x & 63;
    int grp  = lane >> 4;          // 0..3: entry slot
    int u    = lane & 15;          // uint4 within 256B row
    int row0 = blockIdx.x * 64;
    const uint4* xr = (const uint4*)xt;    // row v: xr[v*16 + u]

    // --- phase 1: gather 16 nodes per wave ---
    for (int it = 0; it < 16; ++it) {
        int node = row0 + wave * 16 + it;
        bool valid = node < n_nodes;
        int base = 0, deg = 0;
        if (valid) { base = (int)offsets[node]; deg = degs[node]; }
        int end = base + deg;

        unsigned p0[4], p1[4], p2[4], p3[4];
        #pragma unroll
        for (int d = 0; d < 4; d++) { p0[d]=0u; p1[d]=0u; p2[d]=0u; p3[d]=0u; }

        int i = base + grp;
        for (; i + 12 < end; i += 16) {
            int v0 = nbr[i];
            int v1 = nbr[i + 4];
            int v2 = nbr[i + 8];
            int v3 = nbr[i + 12];
            uint4 w0 = xr[v0 * 16 + u];
            uint4 w1 = xr[v1 * 16 + u];
            uint4 w2 = xr[v2 * 16 + u];
            uint4 w3 = xr[v3 * 16 + u];
            p0[0] = hadd2u(p0[0], w0.x); p1[0] = hadd2u(p1[0], w0.y);
            p2[0] = hadd2u(p2[0], w0.z); p3[0] = hadd2u(p3[0], w0.w);
            p0[1] = hadd2u(p0[1], w1.x); p1[1] = hadd2u(p1[1], w1.y);
            p2[1] = hadd2u(p2[1], w1.z); p3[1] = hadd2u(p3[1], w1.w);
            p0[2] = hadd2u(p0[2], w2.x); p1[2] = hadd2u(p1[2], w2.y);
            p2[2] = hadd2u(p2[2], w2.z); p3[2] = hadd2u(p3[2], w2.w);
            p0[3] = hadd2u(p0[3], w3.x); p1[3] = hadd2u(p1[3], w3.y);
            p2[3] = hadd2u(p2[3], w3.z); p3[3] = hadd2u(p3[3], w3.w);
        }
        for (; i < end; i += 4) {
            int v0 = nbr[i];
            uint4 w0 = xr[v0 * 16 + u];
            p0[0] = hadd2u(p0[0], w0.x); p1[0] = hadd2u(p1[0], w0.y);
            p2[0] = hadd2u(p2[0], w0.z); p3[0] = hadd2u(p3[0], w0.w);
        }

        unsigned s0 = hadd2u(hadd2u(p0[0], p0[1]), hadd2u(p0[2], p0[3]));
        unsigned s1 = hadd2u(hadd2u(p1[0], p1[1]), hadd2u(p1[2], p1[3]));
        unsigned s2 = hadd2u(hadd2u(p2[0], p2[1]), hadd2u(p2[2], p2[3]));
        unsigned s3 = hadd2u(hadd2u(p3[0], p3[1]), hadd2u(p3[2], p3[3]));

        #pragma unroll
        for (int off = 16; off < 64; off <<= 1) {
            s0 = hadd2u(s0, (unsigned)__shfl_xor((int)s0, off));
            s1 = hadd2u(s1, (unsigned)__shfl_xor((int)s1, off));
            s2 = hadd2u(s2, (unsigned)__shfl_xor((int)s2, off));
            s3 = hadd2u(s3, (unsigned)__shfl_xor((int)s3, off));
        }

        if (grp == 0) {
            float inv = 1.0f / fmaxf((float)deg, 1.0f);
            __half2 iv = __float2half2_rn(inv);
            uint4 o;
            o.x = hmul2u(s0, iv);
            o.y = hmul2u(s1, iv);
            o.z = hmul2u(s2, iv);
            o.w = hmul2u(s3, iv);
            *((uint4*)&aS[(wave * 16 + it) * 68 + u * 4]) = o;
        }
    }
    __syncthreads();

    // --- phase 2: MFMA GEMM for this block's 64 rows ---
    int quad = grp;
    int l16  = u;
    int slot = wave * 16 + l16;                       // LDS agg row
    int arow = min(row0 + slot, n_nodes - 1);          // global row (clamped)

    half8 afrag[8];
    #pragma unroll
    for (int kb = 0; kb < 4; kb++)                     // agg half from LDS
        afrag[kb] = *((const half8*)&aS[slot * 68 + kb * 16 + quad * 4]);
    {
        const unsigned short* xrp =
            (const unsigned short*)xt + (size_t)arow * 128 + quad * 8;
        #pragma unroll
        for (int kb = 4; kb < 8; kb++)                 // x half from xt
            afrag[kb] = *((const half8*)(xrp + (kb - 4) * 32));
    }

    f32x4 acc[8];
    #pragma unroll
    for (int f = 0; f < 8; f++) acc[f] = (f32x4){0.f, 0.f, 0.f, 0.f};

    #pragma unroll
    for (int kb = 0; kb < 8; kb++) {
        #pragma unroll
        for (int f = 0; f < 8; f++) {
            int n = f * 16 + l16;
            half8 bfrag = *((const half8*)(Bp + (((size_t)kb * 128 + n) * 4 + quad) * 8));
            acc[f] = __builtin_amdgcn_mfma_f32_16x16x32_f16(afrag[kb], bfrag, acc[f], 0, 0, 0);
        }
    }

    int rbase = row0 + wave * 16 + quad * 4;
    #pragma unroll
    for (int f = 0; f < 8; f++) {
        float bv = bias[f * 16 + l16];
        #pragma unroll
        for (int r = 0; r < 4; r++) {
            int row = rbase + r;
            if (row < n_nodes)
                out[(size_t)row * DIM + f * 16 + l16] = acc[f][r] + bv;
        }
    }
}

extern "C" void kernel_launch(void* const* d_in, const int* in_sizes, int n_in,
                              void* d_out, int out_size, void* d_ws, size_t ws_size,
                              hipStream_t stream) {
    const float* x    = (const float*)d_in[0];
    const int*   edge = (const int*)  d_in[1];
    const float* Wn   = (const float*)d_in[2];
    const float* Ws   = (const float*)d_in[3];
    const float* b    = (const float*)d_in[4];
    float* out = (float*)d_out;

    const int n_nodes = in_sizes[0] / DIM;   // 50000
    const int n_edges = in_sizes[1] / 2;     // 1600000
    const int nb = (n_nodes + 127) >> 7;     // 391

    // ws: entries[nb*CAP] u32 | nbr[nb*CAP] u16 | offsets[N] u32 | degs[N] |
    //     bucket_cur[nb] | Bp (64KB) | xt u32[N*64] (12.8MB).
    unsigned* entries      = (unsigned*)d_ws;
    unsigned short* nbr    = (unsigned short*)(entries + (size_t)nb * CAP);
    unsigned* offsets      = (unsigned*)(nbr + (size_t)nb * CAP);
    int* degs              = (int*)(offsets + n_nodes);
    int* bucket_cur        = degs + n_nodes;
    unsigned short* Bp     = (unsigned short*)((((size_t)(bucket_cur + nb)) + 63) & ~(size_t)63);
    unsigned* xt           = (unsigned*)(Bp + 8 * 128 * 4 * 8);

    const int nprep = n_nodes * 64;          // 3.2M threads covers all 3 jobs
    k_prep<<<(nprep + 255) / 256, 256, 0, stream>>>(Wn, Ws, x, Bp, bucket_cur,
                                                    xt, nb, n_nodes);

    const int bb = (n_edges + EPB - 1) / EPB;   // 391
    k_bin<<<bb, 512, 0, stream>>>(edge, bucket_cur, entries, n_edges, nb);
    k_csort<<<nb, 512, 0, stream>>>(entries, bucket_cur, offsets, degs, nbr, n_nodes);

    const int gb = (n_nodes + 63) / 64;      // 782
    k_gg<<<gb, 256, 0, stream>>>(offsets, degs, nbr, xt, Bp, b, out, n_nodes);
}

// Round 12
// 233.356 us; speedup vs baseline: 1.1461x; 1.1461x over previous
//
#include <hip/hip_runtime.h>
#include <hip/hip_fp16.h>

// GNN mean-aggregate + dual GEMM. N=50000, E=1.6M, DIM=128, fp32 in/out.
// Pipeline (5 launches): k_prep (cursors + pack W + x->f16 x-half of A)
// -> k_bin (bucket bin) -> k_csort (per-bucket counting sort -> u16 CSR)
// -> k_gather (full-width register gather, FROZEN) -> MFMA GEMM.
// FINAL LEDGER (R0-R11):
//  - gather: random-access request-rate bound ~84us, and occupancy-
//    hungry (~8k waves needed; R11 fusion at 3.1k waves -> 143us).
//    L2-resident tiled variants all SLOWER (R5 ~110, R8 103): 64B
//    granules waste L2 transaction capacity. FROZEN at R6 form.
//  - CSR build: two-phase bucket sort mandatory (R9 atomic scatter =
//    300us, full-line RMW). R10 bin: no gaddr array, EPB 4096@512thr.
//  - dur_us includes ~42us harness ws-poison fill (fixed).
//  - gather+gemm fusion FALSIFIED (R11): gemm-tile granularity caps
//    gather occupancy at 31% -> +60us on the gather phase.
//  - Budget: gather 84 + bin/csort ~55 + prep 10 + gemm 15 + fill 42
//    + gaps 20 = 234. All items at measured floor or alternative
//    falsified. R12 = R10 verbatim (best verified: 234.5us).

constexpr int DIM    = 128;
constexpr int NBMAX  = 512;    // coarse buckets (node>>7); N=50000 -> 391
constexpr int EPB    = 4096;   // edges per binning block (512 thr x 8)
constexpr int CAP    = 9216;   // entries per bucket (E[cnt]=8184, ~11 sigma)

typedef _Float16 half8 __attribute__((ext_vector_type(8)));
typedef __attribute__((ext_vector_type(4))) float f32x4;

__device__ __forceinline__ unsigned hadd2u(unsigned a, unsigned b) {
    __half2 ha = *reinterpret_cast<__half2*>(&a);
    __half2 hb = *reinterpret_cast<__half2*>(&b);
    __half2 r  = __hadd2(ha, hb);
    return *reinterpret_cast<unsigned*>(&r);
}
__device__ __forceinline__ unsigned hmul2u(unsigned a, __half2 s) {
    __half2 ha = *reinterpret_cast<__half2*>(&a);
    __half2 r  = __hmul2(ha, s);
    return *reinterpret_cast<unsigned*>(&r);
}
__device__ __forceinline__ unsigned packf16(float x, float y) {
    __half2 h = __floats2half2_rn(x, y);
    return *reinterpret_cast<unsigned*>(&h);
}

// --- K0: fused prep. (a) bucket cursors; (b) pack [Wn;Ws] -> Bp f16
// B-fragments; (c) x fp32 -> f16 x-half of A (abf cols 128..255). ---
__global__ __launch_bounds__(256) void k_prep(
    const float* __restrict__ Wn, const float* __restrict__ Ws,
    const float* __restrict__ x,
    unsigned short* __restrict__ Bp, int* __restrict__ bucket_cur,
    unsigned* __restrict__ abf, int nb, int n_nodes)
{
    int i = blockIdx.x * 256 + threadIdx.x;
    if (i < nb) bucket_cur[i] = i * CAP;
    if (i < 8 * 128 * 4 * 8) {
        int j    = i & 7;
        int quad = (i >> 3) & 3;
        int n    = (i >> 5) & 127;
        int kb   = i >> 12;
        int k = kb * 32 + quad * 8 + j;
        float v = (k < 128) ? Wn[k * 128 + n] : Ws[(k - 128) * 128 + n];
        __half h = __float2half_rn(v);
        Bp[i] = *reinterpret_cast<unsigned short*>(&h);
    }
    if (i < n_nodes * 64) {
        int n = i >> 6;
        int u = i & 63;
        float2 f = ((const float2*)(x + (size_t)n * DIM))[u];
        abf[(size_t)n * 128 + 64 + u] = packf16(f.x, f.y);
    }
}

// --- K1: bin endpoints into fixed-cap buckets. 512 threads, 4096
// edges/block. Entry = (full_node_id<<16) | nbr_id: bucket is
// recomputable (e>>23), so no gaddr staging array is needed.
// Per-wave LDS histogram -> global frontier alloc -> block-local LDS
// counting sort -> coalesced writeback. ---
__global__ __launch_bounds__(512) void k_bin(
    const int* __restrict__ edge, int* __restrict__ bucket_cur,
    unsigned* __restrict__ entries, int n_edges, int nb)
{
    __shared__ int lh[8][NBMAX];          // 16KB: per-wave histograms/cursors
    __shared__ int Lb[NBMAX];             // 2KB: block-local bucket starts
    __shared__ int gb[NBMAX];             // 2KB: global frontier bases
    __shared__ int sc[NBMAX];             // 2KB: bucket-total prefix sums
    __shared__ unsigned sorted[2 * EPB];  // 32KB: block-sorted entries

    int t = threadIdx.x;
    int w = t >> 6;
    for (int i = t; i < 8 * NBMAX; i += 512) ((int*)lh)[i] = 0;
    __syncthreads();

    int e0 = blockIdx.x * EPB;
    int2 ev[8];
    #pragma unroll
    for (int k = 0; k < 8; k++) {
        int idx = e0 + k * 512 + t;
        if (idx < n_edges) {
            ev[k] = ((const int2*)edge)[idx];
            atomicAdd(&lh[w][ev[k].x >> 7], 1);
            atomicAdd(&lh[w][ev[k].y >> 7], 1);
        } else {
            ev[k].x = -1;
        }
    }
    __syncthreads();

    {   // bucket totals (buckets >= nb have zero counts by construction)
        int s = 0;
        #pragma unroll
        for (int ww = 0; ww < 8; ww++) s += lh[ww][t];
        sc[t] = s;
    }
    __syncthreads();
    for (int d = 1; d < 512; d <<= 1) {
        int v = (t >= d) ? sc[t - d] : 0;
        __syncthreads();
        if (t >= d) sc[t] += v;
        __syncthreads();
    }
    if (t < nb) {
        int tot = 0;
        #pragma unroll
        for (int ww = 0; ww < 8; ww++) tot += lh[ww][t];
        int L = sc[t] - tot;
        Lb[t] = L;
        gb[t] = tot ? atomicAdd(&bucket_cur[t], tot) : 0;
        int run = L;
        #pragma unroll
        for (int ww = 0; ww < 8; ww++) { int c = lh[ww][t]; lh[ww][t] = run; run += c; }
    }
    __syncthreads();

    #pragma unroll
    for (int k = 0; k < 8; k++) {
        int a = ev[k].x;
        if (a < 0) continue;
        int b = ev[k].y;
        int sa = atomicAdd(&lh[w][a >> 7], 1);
        sorted[sa] = ((unsigned)a << 16) | (unsigned)b;
        int sb = atomicAdd(&lh[w][b >> 7], 1);
        sorted[sb] = ((unsigned)b << 16) | (unsigned)a;
    }
    __syncthreads();

    int cntb = sc[511];
    for (int p = t; p < cntb; p += 512) {
        unsigned e = sorted[p];
        int bk = (int)(e >> 23);
        entries[gb[bk] + p - Lb[bk]] = e;
    }
}

// --- K2: per-bucket counting sort, 512 threads, 8-way privatized cursors.
// Local node id within bucket = (e>>16)&127 (entry carries full node id). ---
__global__ __launch_bounds__(512) void k_csort(
    const unsigned* __restrict__ entries, const int* __restrict__ bucket_cur,
    unsigned* __restrict__ offsets, int* __restrict__ degs,
    unsigned short* __restrict__ nbr, int n_nodes)
{
    int b    = blockIdx.x;
    int base = b * CAP;
    int cnt  = bucket_cur[b] - base;
    __shared__ int lh[8][128];
    __shared__ int scn[128];
    int t = threadIdx.x;
    int w = t >> 6;
    for (int i = t; i < 8 * 128; i += 512) ((int*)lh)[i] = 0;
    __syncthreads();
    for (int i = t; i < cnt; i += 512)
        atomicAdd(&lh[w][(entries[base + i] >> 16) & 127], 1);
    __syncthreads();
    int tot = 0;
    if (t < 128) {
        #pragma unroll
        for (int ww = 0; ww < 8; ww++) tot += lh[ww][t];
        scn[t] = tot;
    }
    __syncthreads();
    for (int d = 1; d < 128; d <<= 1) {
        int u = (t >= d && t < 128) ? scn[t - d] : 0;
        __syncthreads();
        if (t >= d && t < 128) scn[t] += u;
        __syncthreads();
    }
    if (t < 128) {
        int excl = scn[t] - tot;
        int node = (b << 7) + t;
        if (node < n_nodes) {
            offsets[node] = (unsigned)(base + excl);
            degs[node]    = tot;
        }
        int run = excl;
        #pragma unroll
        for (int ww = 0; ww < 8; ww++) { int c = lh[ww][t]; lh[ww][t] = run; run += c; }
    }
    __syncthreads();
    for (int i = t; i < cnt; i += 512) {
        unsigned e = entries[base + i];
        int slot = atomicAdd(&lh[w][(e >> 16) & 127], 1);
        nbr[base + slot] = (unsigned short)(e & 0xFFFFu);
    }
}

// --- K4 (FROZEN, R6): full-width gather + mean. 1 wave/node, 4 entry
// groups x 16 lanes x 16B = 256B coalesced f16 row per entry, read
// straight from the x-half of abf. 4 depth-slot accumulators. ---
__global__ __launch_bounds__(256) void k_gather(
    const unsigned* __restrict__ offsets,
    const int* __restrict__ degs,
    const unsigned short* __restrict__ nbr,
    unsigned* __restrict__ abf, int n_nodes)
{
    int node = blockIdx.x * 4 + (threadIdx.x >> 6);
    if (node >= n_nodes) return;
    int lane = threadIdx.x & 63;
    int grp  = lane >> 4;          // 0..3: entry slot within iteration
    int u    = lane & 15;          // uint4 within the 256B row
    const uint4* xr = (const uint4*)abf;   // row v x-half: xr[v*32 + 16 + u]
    int base = (int)offsets[node];
    int deg  = degs[node];
    int end  = base + deg;

    // p{c}[d]: accumulator for uint4-component c, depth-slot d
    unsigned p0[4], p1[4], p2[4], p3[4];
    #pragma unroll
    for (int d = 0; d < 4; d++) { p0[d] = 0u; p1[d] = 0u; p2[d] = 0u; p3[d] = 0u; }

    int i = base + grp;
    for (; i + 12 < end; i += 16) {
        int v0 = nbr[i];
        int v1 = nbr[i + 4];
        int v2 = nbr[i + 8];
        int v3 = nbr[i + 12];
        uint4 w0 = xr[v0 * 32 + 16 + u];
        uint4 w1 = xr[v1 * 32 + 16 + u];
        uint4 w2 = xr[v2 * 32 + 16 + u];
        uint4 w3 = xr[v3 * 32 + 16 + u];
        p0[0] = hadd2u(p0[0], w0.x); p1[0] = hadd2u(p1[0], w0.y);
        p2[0] = hadd2u(p2[0], w0.z); p3[0] = hadd2u(p3[0], w0.w);
        p0[1] = hadd2u(p0[1], w1.x); p1[1] = hadd2u(p1[1], w1.y);
        p2[1] = hadd2u(p2[1], w1.z); p3[1] = hadd2u(p3[1], w1.w);
        p0[2] = hadd2u(p0[2], w2.x); p1[2] = hadd2u(p1[2], w2.y);
        p2[2] = hadd2u(p2[2], w2.z); p3[2] = hadd2u(p3[2], w2.w);
        p0[3] = hadd2u(p0[3], w3.x); p1[3] = hadd2u(p1[3], w3.y);
        p2[3] = hadd2u(p2[3], w3.z); p3[3] = hadd2u(p3[3], w3.w);
    }
    for (; i < end; i += 4) {
        int v0 = nbr[i];
        uint4 w0 = xr[v0 * 32 + 16 + u];
        p0[0] = hadd2u(p0[0], w0.x); p1[0] = hadd2u(p1[0], w0.y);
        p2[0] = hadd2u(p2[0], w0.z); p3[0] = hadd2u(p3[0], w0.w);
    }

    // merge depth slots (2-level tree)
    unsigned s0 = hadd2u(hadd2u(p0[0], p0[1]), hadd2u(p0[2], p0[3]));
    unsigned s1 = hadd2u(hadd2u(p1[0], p1[1]), hadd2u(p1[2], p1[3]));
    unsigned s2 = hadd2u(hadd2u(p2[0], p2[1]), hadd2u(p2[2], p2[3]));
    unsigned s3 = hadd2u(hadd2u(p3[0], p3[1]), hadd2u(p3[2], p3[3]));

    // reduce across 4 groups (lane bits 4,5)
    #pragma unroll
    for (int off = 16; off < 64; off <<= 1) {
        s0 = hadd2u(s0, (unsigned)__shfl_xor((int)s0, off));
        s1 = hadd2u(s1, (unsigned)__shfl_xor((int)s1, off));
        s2 = hadd2u(s2, (unsigned)__shfl_xor((int)s2, off));
        s3 = hadd2u(s3, (unsigned)__shfl_xor((int)s3, off));
    }

    if (grp == 0) {
        float inv = 1.0f / fmaxf((float)deg, 1.0f);
        __half2 iv = __float2half2_rn(inv);
        uint4 o;
        o.x = hmul2u(s0, iv);
        o.y = hmul2u(s1, iv);
        o.z = hmul2u(s2, iv);
        o.w = hmul2u(s3, iv);
        ((uint4*)(abf + (size_t)node * 128))[u] = o;
    }
}

// --- K5: MFMA f16 GEMM in-place on d_out. A = abf [n][256] f16. ---
__global__ __launch_bounds__(256) void k_mfma_gemm(
    const unsigned short* __restrict__ abf,
    const unsigned short* __restrict__ Bp,
    const float* __restrict__ bias,
    float* __restrict__ out, int n_nodes)
{
    int wave = threadIdx.x >> 6;
    int lane = threadIdx.x & 63;
    int quad = lane >> 4;
    int l16  = lane & 15;
    int row0 = blockIdx.x * 64 + wave * 16;

    int arow = min(row0 + l16, n_nodes - 1);
    const unsigned short* arp = abf + (size_t)arow * 256 + quad * 8;
    half8 afrag[8];
    #pragma unroll
    for (int kb = 0; kb < 8; kb++)
        afrag[kb] = *((const half8*)(arp + kb * 32));

    f32x4 acc[8];
    #pragma unroll
    for (int f = 0; f < 8; f++) acc[f] = (f32x4){0.f, 0.f, 0.f, 0.f};

    #pragma unroll
    for (int kb = 0; kb < 8; kb++) {
        #pragma unroll
        for (int f = 0; f < 8; f++) {
            int n = f * 16 + l16;
            half8 bfrag = *((const half8*)(Bp + (((size_t)kb * 128 + n) * 4 + quad) * 8));
            acc[f] = __builtin_amdgcn_mfma_f32_16x16x32_f16(afrag[kb], bfrag, acc[f], 0, 0, 0);
        }
    }

    #pragma unroll
    for (int f = 0; f < 8; f++) {
        float bv = bias[f * 16 + l16];
        #pragma unroll
        for (int r = 0; r < 4; r++) {
            int row = row0 + quad * 4 + r;
            if (row < n_nodes)
                out[(size_t)row * DIM + f * 16 + l16] = acc[f][r] + bv;
        }
    }
}

extern "C" void kernel_launch(void* const* d_in, const int* in_sizes, int n_in,
                              void* d_out, int out_size, void* d_ws, size_t ws_size,
                              hipStream_t stream) {
    const float* x    = (const float*)d_in[0];
    const int*   edge = (const int*)  d_in[1];
    const float* Wn   = (const float*)d_in[2];
    const float* Ws   = (const float*)d_in[3];
    const float* b    = (const float*)d_in[4];
    float* out = (float*)d_out;

    const int n_nodes = in_sizes[0] / DIM;   // 50000
    const int n_edges = in_sizes[1] / 2;     // 1600000
    const int nb = (n_nodes + 127) >> 7;     // 391

    // ws: entries[nb*CAP] u32 | nbr[nb*CAP] u16 | offsets[N] u32 | degs[N] |
    //     bucket_cur[nb] | Bp (64KB).
    unsigned* entries      = (unsigned*)d_ws;
    unsigned short* nbr    = (unsigned short*)(entries + (size_t)nb * CAP);
    unsigned* offsets      = (unsigned*)(nbr + (size_t)nb * CAP);
    int* degs              = (int*)(offsets + n_nodes);
    int* bucket_cur        = degs + n_nodes;
    unsigned short* Bp     = (unsigned short*)((((size_t)(bucket_cur + nb)) + 63) & ~(size_t)63);
    unsigned* abf          = (unsigned*)d_out;

    const int nprep = n_nodes * 64;          // 3.2M threads covers all 3 jobs
    k_prep<<<(nprep + 255) / 256, 256, 0, stream>>>(Wn, Ws, x, Bp, bucket_cur,
                                                    abf, nb, n_nodes);

    const int bb = (n_edges + EPB - 1) / EPB;   // 391
    k_bin<<<bb, 512, 0, stream>>>(edge, bucket_cur, entries, n_edges, nb);
    k_csort<<<nb, 512, 0, stream>>>(entries, bucket_cur, offsets, degs, nbr, n_nodes);

    k_gather<<<(n_nodes + 3) / 4, 256, 0, stream>>>(offsets, degs, nbr, abf, n_nodes);

    const int mb = (n_nodes + 63) / 64;
    k_mfma_gemm<<<mb, 256, 0, stream>>>((const unsigned short*)abf, Bp, b,
                                        out, n_nodes);
}